// Round 9
// baseline (3388.882 us; speedup 1.0000x reference)
//
#include <hip/hip_runtime.h>
#include <math.h>

#define NA      128
#define NBATCH  2048
#define NTHR    512
#define NIT     300
#define NBIS    40
#define LRC     0.02f
#define EPSC    1e-8f

// ---- wave64 cross-lane reductions via DPP (VALU pipe, no LDS traffic) ----
template <int CTRL>
__device__ __forceinline__ float dpp_sum_step(float x) {
  int s = __builtin_amdgcn_update_dpp(0, __float_as_int(x), CTRL, 0xF, 0xF, true);
  return x + __int_as_float(s);
}
__device__ __forceinline__ float wave_sum64(float x) {
  x = dpp_sum_step<0x111>(x);
  x = dpp_sum_step<0x112>(x);
  x = dpp_sum_step<0x114>(x);
  x = dpp_sum_step<0x118>(x);
  x = dpp_sum_step<0x142>(x);
  x = dpp_sum_step<0x143>(x);
  return x;  // total in lane 63
}
template <int CTRL>
__device__ __forceinline__ float dpp_mov_self(float x) {
  int s = __builtin_amdgcn_update_dpp(__float_as_int(x), __float_as_int(x), CTRL, 0xF, 0xF, false);
  return __int_as_float(s);
}
__device__ __forceinline__ float wave_min64(float x) {
  x = fminf(x, dpp_mov_self<0x111>(x));
  x = fminf(x, dpp_mov_self<0x112>(x));
  x = fminf(x, dpp_mov_self<0x114>(x));
  x = fminf(x, dpp_mov_self<0x118>(x));
  x = fminf(x, dpp_mov_self<0x142>(x));
  x = fminf(x, dpp_mov_self<0x143>(x));
  return x;
}
__device__ __forceinline__ float wave_max64(float x) {
  x = fmaxf(x, dpp_mov_self<0x111>(x));
  x = fmaxf(x, dpp_mov_self<0x112>(x));
  x = fmaxf(x, dpp_mov_self<0x114>(x));
  x = fmaxf(x, dpp_mov_self<0x118>(x));
  x = fmaxf(x, dpp_mov_self<0x142>(x));
  x = fmaxf(x, dpp_mov_self<0x143>(x));
  return x;
}
__device__ __forceinline__ float bcast63(float x) {
  return __int_as_float(__builtin_amdgcn_readlane(__float_as_int(x), 63));
}
__device__ __forceinline__ float clip1(float x) {
  return __builtin_amdgcn_fmed3f(x, -1.0f, 1.0f);  // c = MAX_WEIGHT = 1
}

// Load one float4 through volatile scalar loads: a volatile load may execute
// EXACTLY once -> the compiler cannot rematerialize/sink it into the loop.
// (R2-R8: launch_bounds, waves_per_eu, opaque asm, and demand-shrinking all
// failed to stop the scheduler from re-reading A every iteration -> 39 GB of
// L3-served traffic at the ~14.5 TB/s Infinity-Cache ceiling = 2.7 ms floor.)
__device__ __forceinline__ float4 vload4(const volatile float* p) {
  float4 q;
  q.x = p[0]; q.y = p[1]; q.z = p[2]; q.w = p[3];
  return q;
}

// One block per batch element, 512 threads (8 waves). Thread (r = tid&127,
// q = tid>>7) owns QUARTER-row r, cols 32q..32q+31 -> 8 float4 = 32 VGPRs,
// total demand ~56 < 64 -> still 8 waves/SIMD, 4 blocks/CU.
__global__ __launch_bounds__(NTHR)
void markowitz_kernel(
    const float* __restrict__ rets,
    const float* __restrict__ covmat,
    const float* __restrict__ gamma,
    const float* __restrict__ alpha,
    float* __restrict__ out)
{
  const int b    = blockIdx.x;
  const int tid  = threadIdx.x;
  const int r    = tid & (NA - 1);  // row 0..127
  const int q    = tid >> 7;        // quarter 0..3 (uniform within a wave)
  const int lane = tid & 63;
  const int wv   = tid >> 6;        // wave 0..7
  const int chain_wv = b & 7;       // spread bisection chains across SIMDs

  __shared__ __align__(16) float ws[NA];
  __shared__ __align__(16) float vs[NA];
  __shared__ __align__(16) float part[NTHR];
  __shared__ float pp[4];

  // ---- one-time: stage quarter-row of A (gamma folded) via VOLATILE loads ----
  const float gm = gamma[b];
  const volatile float* Aq =
      covmat + (size_t)b * NA * NA + (size_t)r * NA + (size_t)q * 32;
  float4 a0 = vload4(Aq +  0), a1 = vload4(Aq +  4),
         a2 = vload4(Aq +  8), a3 = vload4(Aq + 12),
         a4 = vload4(Aq + 16), a5 = vload4(Aq + 20),
         a6 = vload4(Aq + 24), a7 = vload4(Aq + 28);
  a0.x *= gm; a0.y *= gm; a0.z *= gm; a0.w *= gm;
  a1.x *= gm; a1.y *= gm; a1.z *= gm; a1.w *= gm;
  a2.x *= gm; a2.y *= gm; a2.z *= gm; a2.w *= gm;
  a3.x *= gm; a3.y *= gm; a3.z *= gm; a3.w *= gm;
  a4.x *= gm; a4.y *= gm; a4.z *= gm; a4.w *= gm;
  a5.x *= gm; a5.y *= gm; a5.z *= gm; a5.w *= gm;
  a6.x *= gm; a6.y *= gm; a6.z *= gm; a6.w *= gm;
  a7.x *= gm; a7.y *= gm; a7.z *= gm; a7.w *= gm;

  const float av = fabsf(alpha[b]);
  float r_c = 0.0f;
  if (tid < NA) { r_c = rets[b * NA + tid]; ws[tid] = 1.0f / NA; }
  __syncthreads();

#pragma unroll 1
  for (int it = 0; it < NIT; ++it) {
    // ---- 1. quarter-row dot (A in regs; w via wave-uniform LDS broadcast) ----
    const float4* w4 = reinterpret_cast<const float4*>(ws) + q * 8;
    float4 acc = make_float4(0.f, 0.f, 0.f, 0.f);
    {
      float4 wk;
      wk = w4[0]; acc.x = fmaf(a0.x, wk.x, acc.x); acc.y = fmaf(a0.y, wk.y, acc.y);
                  acc.z = fmaf(a0.z, wk.z, acc.z); acc.w = fmaf(a0.w, wk.w, acc.w);
      wk = w4[1]; acc.x = fmaf(a1.x, wk.x, acc.x); acc.y = fmaf(a1.y, wk.y, acc.y);
                  acc.z = fmaf(a1.z, wk.z, acc.z); acc.w = fmaf(a1.w, wk.w, acc.w);
      wk = w4[2]; acc.x = fmaf(a2.x, wk.x, acc.x); acc.y = fmaf(a2.y, wk.y, acc.y);
                  acc.z = fmaf(a2.z, wk.z, acc.z); acc.w = fmaf(a2.w, wk.w, acc.w);
      wk = w4[3]; acc.x = fmaf(a3.x, wk.x, acc.x); acc.y = fmaf(a3.y, wk.y, acc.y);
                  acc.z = fmaf(a3.z, wk.z, acc.z); acc.w = fmaf(a3.w, wk.w, acc.w);
      wk = w4[4]; acc.x = fmaf(a4.x, wk.x, acc.x); acc.y = fmaf(a4.y, wk.y, acc.y);
                  acc.z = fmaf(a4.z, wk.z, acc.z); acc.w = fmaf(a4.w, wk.w, acc.w);
      wk = w4[5]; acc.x = fmaf(a5.x, wk.x, acc.x); acc.y = fmaf(a5.y, wk.y, acc.y);
                  acc.z = fmaf(a5.z, wk.z, acc.z); acc.w = fmaf(a5.w, wk.w, acc.w);
      wk = w4[6]; acc.x = fmaf(a6.x, wk.x, acc.x); acc.y = fmaf(a6.y, wk.y, acc.y);
                  acc.z = fmaf(a6.z, wk.z, acc.z); acc.w = fmaf(a6.w, wk.w, acc.w);
      wk = w4[7]; acc.x = fmaf(a7.x, wk.x, acc.x); acc.y = fmaf(a7.y, wk.y, acc.y);
                  acc.z = fmaf(a7.z, wk.z, acc.z); acc.w = fmaf(a7.w, wk.w, acc.w);
    }
    part[tid] = (acc.x + acc.y) + (acc.z + acc.w);
    __syncthreads();

    // ---- 2. combine quarters; wAw / ww reductions (waves 0,1) ----
    float Aw = 0.f, w_c = 0.f, v_c = 0.f;
    if (tid < NA) {
      Aw  = (part[tid] + part[tid + NA]) + (part[tid + 2 * NA] + part[tid + 3 * NA]);
      w_c = ws[tid];
      float p1 = wave_sum64(w_c * Aw);
      float p2 = wave_sum64(w_c * w_c);
      if (lane == 63) { pp[wv * 2 + 0] = p1; pp[wv * 2 + 1] = p2; }
    }
    __syncthreads();

    // ---- 3. gradient step -> v (waves 0,1) ----
    if (tid < NA) {
      const float risk = sqrtf(pp[0] + pp[2] + EPSC);
      const float nrm  = sqrtf(pp[1] + pp[3] + EPSC);
      const float g    = r_c - Aw / risk - av * (w_c / nrm);
      v_c = w_c + LRC * g;
      vs[tid] = v_c;
    }
    __syncthreads();

    // ---- 4. bisection + projection on the chain wave only ----
    if (wv == chain_wv) {
      float v0 = vs[lane];
      float v1 = vs[lane + 64];
      float mn = bcast63(wave_min64(fminf(v0, v1)));
      float mx = bcast63(wave_max64(fmaxf(v0, v1)));
      float lo = mn - 2.0f;   // min(v) - c - 1
      float hi = mx + 1.0f;   // max(v) + c
#pragma unroll 1
      for (int rr = 0; rr < NBIS; ++rr) {
        const float mid = 0.5f * (lo + hi);
        float s = wave_sum64(clip1(v0 - mid) + clip1(v1 - mid));
        const float st = bcast63(s);
        const bool big = st > 1.0f;
        const float nlo = big ? mid : lo;
        const float nhi = big ? hi : mid;
        // Fixed point: bracket unchanged -> every remaining round is a
        // bit-identical no-op (mid recomputes identically). Exact early exit.
        if (nlo == lo && nhi == hi) break;
        lo = nlo; hi = nhi;
      }
      const float tau = 0.5f * (lo + hi);
      ws[lane]      = clip1(v0 - tau);
      ws[lane + 64] = clip1(v1 - tau);
    }
    __syncthreads();
  }

  if (tid < NA) out[b * NA + tid] = ws[tid];
}

extern "C" void kernel_launch(void* const* d_in, const int* in_sizes, int n_in,
                              void* d_out, int out_size, void* d_ws, size_t ws_size,
                              hipStream_t stream) {
  const float* rets   = (const float*)d_in[0];
  const float* covmat = (const float*)d_in[1];
  const float* gamma  = (const float*)d_in[2];
  const float* alpha  = (const float*)d_in[3];
  float* out = (float*)d_out;

  hipLaunchKernelGGL(markowitz_kernel, dim3(NBATCH), dim3(NTHR), 0, stream,
                     rets, covmat, gamma, alpha, out);
}

// Round 10
// 3354.490 us; speedup vs baseline: 1.0103x; 1.0103x over previous
//
#include <hip/hip_runtime.h>
#include <math.h>

#define NA      128
#define NBATCH  2048
#define NTHR    256
#define NIT     300
#define NBIS    40
#define LRC     0.02f
#define EPSC    1e-8f

// ---- wave64 cross-lane reductions via DPP (VALU pipe, no LDS traffic) ----
template <int CTRL>
__device__ __forceinline__ float dpp_sum_step(float x) {
  int s = __builtin_amdgcn_update_dpp(0, __float_as_int(x), CTRL, 0xF, 0xF, true);
  return x + __int_as_float(s);
}
__device__ __forceinline__ float wave_sum64(float x) {
  x = dpp_sum_step<0x111>(x);
  x = dpp_sum_step<0x112>(x);
  x = dpp_sum_step<0x114>(x);
  x = dpp_sum_step<0x118>(x);
  x = dpp_sum_step<0x142>(x);
  x = dpp_sum_step<0x143>(x);
  return x;  // total in lane 63
}
template <int CTRL>
__device__ __forceinline__ float dpp_mov_self(float x) {
  int s = __builtin_amdgcn_update_dpp(__float_as_int(x), __float_as_int(x), CTRL, 0xF, 0xF, false);
  return __int_as_float(s);
}
__device__ __forceinline__ float wave_min64(float x) {
  x = fminf(x, dpp_mov_self<0x111>(x));
  x = fminf(x, dpp_mov_self<0x112>(x));
  x = fminf(x, dpp_mov_self<0x114>(x));
  x = fminf(x, dpp_mov_self<0x118>(x));
  x = fminf(x, dpp_mov_self<0x142>(x));
  x = fminf(x, dpp_mov_self<0x143>(x));
  return x;
}
__device__ __forceinline__ float wave_max64(float x) {
  x = fmaxf(x, dpp_mov_self<0x111>(x));
  x = fmaxf(x, dpp_mov_self<0x112>(x));
  x = fmaxf(x, dpp_mov_self<0x114>(x));
  x = fmaxf(x, dpp_mov_self<0x118>(x));
  x = fmaxf(x, dpp_mov_self<0x142>(x));
  x = fmaxf(x, dpp_mov_self<0x143>(x));
  return x;
}
__device__ __forceinline__ float bcast63(float x) {
  return __int_as_float(__builtin_amdgcn_readlane(__float_as_int(x), 63));
}
__device__ __forceinline__ float clip1(float x) {
  return __builtin_amdgcn_fmed3f(x, -1.0f, 1.0f);  // c = MAX_WEIGHT = 1
}

// ---- AGPR pinning ----------------------------------------------------------
// R2-R9 forensic: the compiler refuses to keep a per-thread A-tile in arch
// VGPRs (caps at 100/56/32 regs for 128/256/512-thr blocks, leaving half the
// RF unused) and remats (R2-R8) or scratch-spills (R5/R9-volatile) it ->
// ~39 GB/dispatch of L3-served re-reads at the ~14.7 TB/s ceiling = 2.7 ms.
// Fix: pin A into hardcoded AGPRs a0..a63 via volatile asm. Volatile asm can't
// be rematted/sunk/CSE'd; clobbers make the backend account the AGPRs and keep
// loop-crossing temps out of them. Reads are 1-cyc VALU: A at register speed,
// zero memory traffic. Budget 64 AGPR + ~50 VGPR -> 4 waves/SIMD, 4 blocks/CU.
#define AW2(R, X) asm volatile("v_accvgpr_write_b32 a" #R ", %0" :: "v"(X) : "a" #R)
#define AW(R, X)  AW2(R, X)
#define AR2(R, D) asm volatile("v_accvgpr_read_b32 %0, a" #R : "=v"(D) : : "a" #R)
#define AR(R, D)  AR2(R, D)

#define STAGE(K, R0, R1, R2, R3) do { float4 qq = Ar[K]; \
  AW(R0, qq.x * gm); AW(R1, qq.y * gm); AW(R2, qq.z * gm); AW(R3, qq.w * gm); } while (0)

#define DOT(K, R0, R1, R2, R3) do { const float4 wk = w4[K]; float x0, x1, x2, x3; \
  AR(R0, x0); AR(R1, x1); AR(R2, x2); AR(R3, x3); \
  acc.x = fmaf(x0, wk.x, acc.x); acc.y = fmaf(x1, wk.y, acc.y); \
  acc.z = fmaf(x2, wk.z, acc.z); acc.w = fmaf(x3, wk.w, acc.w); } while (0)

// One block per batch element, 256 threads (4 waves). Thread (r = tid&127,
// h = tid>>7) owns half-row r, cols 64h..64h+63, held in AGPRs a0..a63.
// Per iteration: 2 barriers. Matvec by all waves; combine/reduce/grad/
// bisect/project all on ONE wave (b&3 -> chains spread across SIMDs).
__global__ __launch_bounds__(NTHR)
void markowitz_kernel(
    const float* __restrict__ rets,
    const float* __restrict__ covmat,
    const float* __restrict__ gamma,
    const float* __restrict__ alpha,
    float* __restrict__ out)
{
  const int b     = blockIdx.x;
  const int tid   = threadIdx.x;
  const int r     = tid & (NA - 1);  // row 0..127
  const int h     = tid >> 7;        // half 0/1 (uniform per wave)
  const int lane  = tid & 63;
  const int wv    = tid >> 6;        // wave 0..3
  const int chain = b & 3;           // chain wave -> different SIMD per block

  __shared__ __align__(16) float ws[NA];
  __shared__ __align__(16) float part[NTHR];

  // ---- one-time: stage half-row of A (gamma folded) into AGPRs ----
  const float gm = gamma[b];
  const float4* Ar = reinterpret_cast<const float4*>(
      covmat + (size_t)b * NA * NA + (size_t)r * NA + (size_t)h * 64);
  STAGE( 0,  0,  1,  2,  3);  STAGE( 1,  4,  5,  6,  7);
  STAGE( 2,  8,  9, 10, 11);  STAGE( 3, 12, 13, 14, 15);
  STAGE( 4, 16, 17, 18, 19);  STAGE( 5, 20, 21, 22, 23);
  STAGE( 6, 24, 25, 26, 27);  STAGE( 7, 28, 29, 30, 31);
  STAGE( 8, 32, 33, 34, 35);  STAGE( 9, 36, 37, 38, 39);
  STAGE(10, 40, 41, 42, 43);  STAGE(11, 44, 45, 46, 47);
  STAGE(12, 48, 49, 50, 51);  STAGE(13, 52, 53, 54, 55);
  STAGE(14, 56, 57, 58, 59);  STAGE(15, 60, 61, 62, 63);

  // chain-wave state (loaded by every wave; only `chain` uses it)
  const float av = fabsf(alpha[b]);
  const float rA = rets[b * NA + lane];
  const float rB = rets[b * NA + lane + 64];

  if (tid < NA) ws[tid] = 1.0f / NA;
  __syncthreads();

#pragma unroll 1
  for (int it = 0; it < NIT; ++it) {
    // ---- 1. half-row dot: A from AGPRs, w via wave-uniform LDS broadcast ----
    const float4* w4 = reinterpret_cast<const float4*>(ws) + h * 16;
    float4 acc = make_float4(0.f, 0.f, 0.f, 0.f);
    DOT( 0,  0,  1,  2,  3);  DOT( 1,  4,  5,  6,  7);
    DOT( 2,  8,  9, 10, 11);  DOT( 3, 12, 13, 14, 15);
    DOT( 4, 16, 17, 18, 19);  DOT( 5, 20, 21, 22, 23);
    DOT( 6, 24, 25, 26, 27);  DOT( 7, 28, 29, 30, 31);
    DOT( 8, 32, 33, 34, 35);  DOT( 9, 36, 37, 38, 39);
    DOT(10, 40, 41, 42, 43);  DOT(11, 44, 45, 46, 47);
    DOT(12, 48, 49, 50, 51);  DOT(13, 52, 53, 54, 55);
    DOT(14, 56, 57, 58, 59);  DOT(15, 60, 61, 62, 63);
    part[tid] = (acc.x + acc.y) + (acc.z + acc.w);
    __syncthreads();

    // ---- 2. single chain wave: combine, reduce, grad, bisect, project ----
    if (wv == chain) {
      const float AwA = part[lane] + part[lane + 128];        // row lane
      const float AwB = part[lane + 64] + part[lane + 192];   // row lane+64
      const float wA  = ws[lane];
      const float wB  = ws[lane + 64];
      const float risk = sqrtf(bcast63(wave_sum64(wA * AwA + wB * AwB)) + EPSC);
      const float nrm  = sqrtf(bcast63(wave_sum64(wA * wA + wB * wB)) + EPSC);
      const float gA = rA - AwA / risk - av * (wA / nrm);
      const float gB = rB - AwB / risk - av * (wB / nrm);
      const float vA = wA + LRC * gA;
      const float vB = wB + LRC * gB;
      const float mn = bcast63(wave_min64(fminf(vA, vB)));
      const float mx = bcast63(wave_max64(fmaxf(vA, vB)));
      float lo = mn - 2.0f;   // min(v) - c - 1
      float hi = mx + 1.0f;   // max(v) + c
#pragma unroll 1
      for (int rr = 0; rr < NBIS; ++rr) {
        const float mid = 0.5f * (lo + hi);
        const float st  = bcast63(wave_sum64(clip1(vA - mid) + clip1(vB - mid)));
        const bool  big = st > 1.0f;
        const float nlo = big ? mid : lo;
        const float nhi = big ? hi : mid;
        // Fixed point: bracket unchanged -> all remaining rounds are
        // bit-identical no-ops. Exact early exit (output unchanged).
        if (nlo == lo && nhi == hi) break;
        lo = nlo; hi = nhi;
      }
      const float tau = 0.5f * (lo + hi);
      ws[lane]      = clip1(vA - tau);
      ws[lane + 64] = clip1(vB - tau);
    }
    __syncthreads();
  }

  if (tid < NA) out[b * NA + tid] = ws[tid];
}

extern "C" void kernel_launch(void* const* d_in, const int* in_sizes, int n_in,
                              void* d_out, int out_size, void* d_ws, size_t ws_size,
                              hipStream_t stream) {
  const float* rets   = (const float*)d_in[0];
  const float* covmat = (const float*)d_in[1];
  const float* gamma  = (const float*)d_in[2];
  const float* alpha  = (const float*)d_in[3];
  float* out = (float*)d_out;

  hipLaunchKernelGGL(markowitz_kernel, dim3(NBATCH), dim3(NTHR), 0, stream,
                     rets, covmat, gamma, alpha, out);
}